// Round 10
// baseline (297.307 us; speedup 1.0000x reference)
//
#include <hip/hip_runtime.h>
#include <math.h>

#define THREADS 256
#define INV_SQRT2 0.70710678118654752440f

typedef float f32x4 __attribute__((ext_vector_type(4)));

__device__ __forceinline__ void nt_store4(const float4& v, float4* p) {
    f32x4 w = { v.x, v.y, v.z, v.w };
    __builtin_nontemporal_store(w, (f32x4*)p);
}

// ---- monotonic float<->uint key transform (ascending order preserved) ----
__device__ __forceinline__ unsigned f2key(float f) {
    unsigned u = __float_as_uint(f);
    return (u & 0x80000000u) ? ~u : (u | 0x80000000u);
}
__device__ __forceinline__ float key2f(unsigned k) {
    unsigned u = (k & 0x80000000u) ? (k & 0x7fffffffu) : ~k;
    return __uint_as_float(u);
}

__device__ __forceinline__ float gelu_erf(float v) {
    return 0.5f * v * (1.0f + erff(v * INV_SQRT2));
}

// Zero ws header (kernel, not hipMemsetAsync: memset graph node cost ~34 us).
__global__ void __launch_bounds__(THREADS) k_zero(unsigned* __restrict__ p, int n) {
    int i = blockIdx.x * THREADS + threadIdx.x;
    if (i < n) p[i] = 0;
}

// ======================= FAST PATH (sample-guided, 1 wide pass) ============
// sel[]: 0=b1lo, 1=b1hi, 2=b2(rel bin), 3=k2, 4=kthkey

#define SAMPLE_BLOCKS 256
#define SAMPLE_PER_THREAD 8
// samples = 256*256*8 float4 = 524288 float4 = 2,097,152 floats (1/16 stride)

// S0: 12-bit histogram (key bits 31:20) of a 1/16 strided subsample.
__global__ void __launch_bounds__(THREADS) k_sample_hist(
    const float4* __restrict__ x, unsigned* __restrict__ h12s, long long n4)
{
    __shared__ unsigned lh[4096];
    for (int i = threadIdx.x; i < 4096; i += THREADS) lh[i] = 0;
    __syncthreads();
    const unsigned g = blockIdx.x * THREADS + threadIdx.x;        // [0, 65536)
    #pragma unroll
    for (int s = 0; s < SAMPLE_PER_THREAD; ++s) {
        long long idx = ((long long)s * (SAMPLE_BLOCKS * THREADS) + g) * 16;
        if (idx < n4) {
            float4 v = x[idx];
            atomicAdd(&lh[f2key(v.x) >> 20], 1u);
            atomicAdd(&lh[f2key(v.y) >> 20], 1u);
            atomicAdd(&lh[f2key(v.z) >> 20], 1u);
            atomicAdd(&lh[f2key(v.w) >> 20], 1u);
        }
    }
    __syncthreads();
    for (int b = threadIdx.x; b < 4096; b += THREADS) {
        unsigned s = lh[b];
        if (s) atomicAdd(&h12s[b], s);
    }
}

// SA: pick candidate bucket window [b1lo, b1hi] = sample bucket +/- 1.
// Sample quantile sigma ~0.0024 << bucket width ~0.0625 -> +/-1 is safe.
__global__ void __launch_bounds__(THREADS) k_selectA(
    const unsigned* __restrict__ h12s, unsigned* __restrict__ sel, long long rank_s)
{
    __shared__ unsigned ps[256];
    const int t = threadIdx.x;
    unsigned s = 0;
    for (int i = 0; i < 16; ++i) s += h12s[t * 16 + i];
    ps[t] = s;
    __syncthreads();
    if (t == 0) {
        unsigned run = 0;
        for (int i = 0; i < 256; ++i) { unsigned c = ps[i]; ps[i] = run; run += c; }
    }
    __syncthreads();
    long long base = (long long)ps[t];
    for (int i = 0; i < 16; ++i) {
        unsigned c = h12s[t * 16 + i];
        if (base < rank_s && rank_s <= base + (long long)c) {
            int B = t * 16 + i;
            sel[0] = (unsigned)(B > 0 ? B - 1 : 0);
            sel[1] = (unsigned)(B < 4095 ? B + 1 : 4095);
        }
        base += (long long)c;
    }
}

#define CBUF 2048   // per-block candidate staging; E ~550/block for 3 buckets

// W: THE single wide pass. Read x once; NT-write gelu; NT-write tentative
// x_saved; exact below-window count; compact in-window candidates (key,idx).
// No LDS histogram, 16KB LDS -> high occupancy pure-stream kernel.
__global__ void __launch_bounds__(THREADS) k_fused_all(
    const float4* __restrict__ x, float4* __restrict__ outg, float4* __restrict__ outs,
    const unsigned* __restrict__ sel,
    uint2* __restrict__ cand, unsigned* __restrict__ ccnt, unsigned* __restrict__ below_g,
    unsigned cap, long long n4)
{
    __shared__ uint2 sc[CBUF];
    __shared__ unsigned s_cnt, s_n, s_base;
    __shared__ unsigned sb[THREADS];
    const unsigned b1lo = sel[0], b1hi = sel[1];
    if (threadIdx.x == 0) s_cnt = 0;
    __syncthreads();
    unsigned below = 0;
    const long long stride = (long long)gridDim.x * THREADS;
    for (long long i = (long long)blockIdx.x * THREADS + threadIdx.x; i < n4; i += stride) {
        float4 v = x[i];
        float4 g, r;
        const float* vp = (const float*)&v;
        float* gp = (float*)&g;
        float* rp = (float*)&r;
        #pragma unroll
        for (int c = 0; c < 4; ++c) {
            float val = vp[c];
            gp[c] = gelu_erf(val);
            unsigned k = f2key(val);
            unsigned pre = k >> 20;
            rp[c] = (pre > b1hi) ? val : -10.0f;   // window fixed up in finalize
            if (pre < b1lo) {
                ++below;
            } else if (pre <= b1hi) {
                unsigned pos = atomicAdd(&s_cnt, 1u);
                if (pos < CBUF) sc[pos] = make_uint2(k, (unsigned)(i * 4 + c));
            }
        }
        nt_store4(g, &outg[i]);
        nt_store4(r, &outs[i]);
    }
    sb[threadIdx.x] = below;
    __syncthreads();
    // tree-reduce below
    for (int off = THREADS / 2; off > 0; off >>= 1) {
        if (threadIdx.x < off) sb[threadIdx.x] += sb[threadIdx.x + off];
        __syncthreads();
    }
    if (threadIdx.x == 0) {
        atomicAdd(below_g, sb[0]);
        unsigned cnt = s_cnt < CBUF ? s_cnt : CBUF;
        s_n = cnt;
        s_base = atomicAdd(ccnt, cnt);
    }
    __syncthreads();
    const unsigned base = s_base, nn = s_n;
    for (unsigned j = threadIdx.x; j < nn; j += THREADS) {
        unsigned d = base + j;
        if (d < cap) cand[d] = sc[j];
    }
}

// C1: 12288-bin histogram of candidate rel-keys ((k - b1lo<<20) >> 8).
__global__ void __launch_bounds__(THREADS) k_cand_hist(
    const uint2* __restrict__ cand, const unsigned* __restrict__ ccnt, unsigned cap,
    const unsigned* __restrict__ sel, unsigned* __restrict__ h12b)
{
    __shared__ unsigned lh[12288];
    const unsigned base_key = sel[0] << 20;
    for (int i = threadIdx.x; i < 12288; i += THREADS) lh[i] = 0;
    __syncthreads();
    unsigned n = *ccnt; if (n > cap) n = cap;
    const unsigned stride = gridDim.x * THREADS;
    for (unsigned j = blockIdx.x * THREADS + threadIdx.x; j < n; j += stride) {
        unsigned rel = cand[j].x - base_key;     // < 3<<20 by construction
        atomicAdd(&lh[rel >> 8], 1u);
    }
    __syncthreads();
    for (int b = threadIdx.x; b < 12288; b += THREADS) {
        unsigned s = lh[b];
        if (s) atomicAdd(&h12b[b], s);
    }
}

// SB: select rel-bin b2 for rank k1 = k0 - below.
__global__ void __launch_bounds__(THREADS) k_selectB(
    const unsigned* __restrict__ h12b, const unsigned* __restrict__ below_g,
    unsigned* __restrict__ sel, long long k0)
{
    __shared__ unsigned ps[256];
    const int t = threadIdx.x;
    const long long kin = k0 - (long long)(*below_g);
    unsigned s = 0;
    for (int i = 0; i < 48; ++i) s += h12b[t * 48 + i];
    ps[t] = s;
    __syncthreads();
    if (t == 0) {
        unsigned run = 0;
        for (int i = 0; i < 256; ++i) { unsigned c = ps[i]; ps[i] = run; run += c; }
    }
    __syncthreads();
    long long base = (long long)ps[t];
    for (int i = 0; i < 48; ++i) {
        unsigned c = h12b[t * 48 + i];
        if (base < kin && kin <= base + (long long)c) {
            sel[2] = (unsigned)(t * 48 + i);
            sel[3] = (unsigned)(kin - base);
        }
        base += (long long)c;
    }
}

// C2: final 8-bit histogram of candidates in rel-bin b2.
__global__ void __launch_bounds__(THREADS) k_cand_hist8(
    const uint2* __restrict__ cand, const unsigned* __restrict__ ccnt, unsigned cap,
    const unsigned* __restrict__ sel, unsigned* __restrict__ h8c)
{
    __shared__ unsigned lh[256];
    const unsigned base_key = sel[0] << 20;
    const unsigned b2 = sel[2];
    lh[threadIdx.x] = 0;
    __syncthreads();
    unsigned n = *ccnt; if (n > cap) n = cap;
    const unsigned stride = gridDim.x * THREADS;
    for (unsigned j = blockIdx.x * THREADS + threadIdx.x; j < n; j += stride) {
        unsigned rel = cand[j].x - base_key;
        if ((rel >> 8) == b2) atomicAdd(&lh[rel & 0xFFu], 1u);
    }
    __syncthreads();
    unsigned s = lh[threadIdx.x];
    if (s) atomicAdd(&h8c[threadIdx.x], s);
}

// SC: final select -> kthkey + kth scalar output.
__global__ void __launch_bounds__(THREADS) k_selectC(
    const unsigned* __restrict__ h8c, unsigned* __restrict__ sel,
    float* __restrict__ kth_out)
{
    __shared__ unsigned ps[256];
    const int t = threadIdx.x;
    const long long kin = (long long)sel[3];
    unsigned c = h8c[t];
    ps[t] = c;
    __syncthreads();
    if (t == 0) {
        unsigned run = 0;
        for (int i = 0; i < 256; ++i) { unsigned v = ps[i]; ps[i] = run; run += v; }
    }
    __syncthreads();
    long long base = (long long)ps[t];
    if (base < kin && kin <= base + (long long)c) {
        unsigned kthkey = (sel[0] << 20) + (sel[2] << 8) + (unsigned)t;
        sel[4] = kthkey;
        *kth_out = key2f(kthkey);
    }
}

// F: fix up candidate positions of x_saved with exact kthkey.
__global__ void __launch_bounds__(THREADS) k_finalize(
    const uint2* __restrict__ cand, const unsigned* __restrict__ ccnt, unsigned cap,
    float* __restrict__ outs_scalar, const unsigned* __restrict__ sel)
{
    const unsigned kthkey = sel[4];
    unsigned n = *ccnt; if (n > cap) n = cap;
    const unsigned stride = gridDim.x * THREADS;
    for (unsigned j = blockIdx.x * THREADS + threadIdx.x; j < n; j += stride) {
        uint2 c = cand[j];
        outs_scalar[c.y] = (c.x > kthkey) ? key2f(c.x) : -10.0f;
    }
}

// ======================= FALLBACK PATH (R1, proven) ========================

__device__ void block_select(const unsigned* __restrict__ hist, int chunk,
                             long long kin, unsigned* bucket_out, long long* krem_out) {
    __shared__ unsigned s_ps[256];
    __shared__ unsigned s_bucket;
    __shared__ unsigned s_krem;
    const int t = threadIdx.x;
    const unsigned* h = hist + (size_t)t * chunk;
    unsigned s = 0;
    for (int i = 0; i < chunk; ++i) s += h[i];
    s_ps[t] = s;
    __syncthreads();
    if (t == 0) {
        unsigned run = 0;
        for (int i = 0; i < 256; ++i) { unsigned c = s_ps[i]; s_ps[i] = run; run += c; }
    }
    __syncthreads();
    long long base = (long long)s_ps[t];
    for (int i = 0; i < chunk; ++i) {
        unsigned c = h[i];
        if (base < kin && kin <= base + (long long)c) {
            s_bucket = (unsigned)(t * chunk + i);
            s_krem = (unsigned)(kin - base);
        }
        base += (long long)c;
    }
    __syncthreads();
    *bucket_out = s_bucket;
    *krem_out = (long long)s_krem;
    __syncthreads();
}

__global__ void __launch_bounds__(THREADS) k_gelu_hist8(
    const float4* __restrict__ x, float4* __restrict__ out,
    unsigned* __restrict__ hist8, long long n4)
{
    __shared__ unsigned lh[256 * 4];
    for (int i = threadIdx.x; i < 256 * 4; i += THREADS) lh[i] = 0;
    __syncthreads();
    const int c = threadIdx.x & 3;
    const long long stride = (long long)gridDim.x * THREADS;
    for (long long i = (long long)blockIdx.x * THREADS + threadIdx.x; i < n4; i += stride) {
        float4 v = x[i];
        float4 g;
        g.x = gelu_erf(v.x);
        g.y = gelu_erf(v.y);
        g.z = gelu_erf(v.z);
        g.w = gelu_erf(v.w);
        out[i] = g;
        atomicAdd(&lh[((f2key(v.x) >> 24) << 2) + c], 1u);
        atomicAdd(&lh[((f2key(v.y) >> 24) << 2) + c], 1u);
        atomicAdd(&lh[((f2key(v.z) >> 24) << 2) + c], 1u);
        atomicAdd(&lh[((f2key(v.w) >> 24) << 2) + c], 1u);
    }
    __syncthreads();
    const int t = threadIdx.x;
    unsigned s = lh[t * 4] + lh[t * 4 + 1] + lh[t * 4 + 2] + lh[t * 4 + 3];
    if (s) atomicAdd(&hist8[t], s);
}

__global__ void __launch_bounds__(THREADS) k_hist12_fb(
    const float4* __restrict__ x, long long n4, long long k0,
    const unsigned* __restrict__ h8, const unsigned* __restrict__ h12a,
    unsigned* __restrict__ hist_out, int stage)
{
    __shared__ unsigned lh[4096];
    unsigned b1; long long k1;
    block_select(h8, 1, k0, &b1, &k1);
    unsigned matchval = b1;
    int matchshift = 24;
    if (stage == 1) {
        unsigned b2; long long k2;
        block_select(h12a, 16, k1, &b2, &k2);
        matchval = (b1 << 12) | b2;
        matchshift = 12;
    }
    for (int i = threadIdx.x; i < 4096; i += THREADS) lh[i] = 0;
    __syncthreads();
    const int binshift = matchshift - 12;
    const long long stride = (long long)gridDim.x * THREADS;
    for (long long i = (long long)blockIdx.x * THREADS + threadIdx.x; i < n4; i += stride) {
        float4 v = x[i];
        unsigned k;
        k = f2key(v.x); if ((k >> matchshift) == matchval) atomicAdd(&lh[(k >> binshift) & 0xFFFu], 1u);
        k = f2key(v.y); if ((k >> matchshift) == matchval) atomicAdd(&lh[(k >> binshift) & 0xFFFu], 1u);
        k = f2key(v.z); if ((k >> matchshift) == matchval) atomicAdd(&lh[(k >> binshift) & 0xFFFu], 1u);
        k = f2key(v.w); if ((k >> matchshift) == matchval) atomicAdd(&lh[(k >> binshift) & 0xFFFu], 1u);
    }
    __syncthreads();
    for (int i = threadIdx.x; i < 4096; i += THREADS) {
        unsigned s = lh[i];
        if (s) atomicAdd(&hist_out[i], s);
    }
}

__global__ void __launch_bounds__(THREADS) k_xsaved_fb(
    const float4* __restrict__ x, float4* __restrict__ out, float* __restrict__ kth_out,
    const unsigned* __restrict__ h8, const unsigned* __restrict__ h12a,
    const unsigned* __restrict__ h12b, long long k0, long long n4)
{
    unsigned b1, b2, b3; long long k1, k2, k3;
    block_select(h8, 1, k0, &b1, &k1);
    block_select(h12a, 16, k1, &b2, &k2);
    block_select(h12b, 16, k2, &b3, &k3);
    const unsigned key = (b1 << 24) | (b2 << 12) | b3;
    const float kth = key2f(key);
    if (blockIdx.x == 0 && threadIdx.x == 0) *kth_out = kth;
    const long long stride = (long long)gridDim.x * THREADS;
    for (long long i = (long long)blockIdx.x * THREADS + threadIdx.x; i < n4; i += stride) {
        float4 v = x[i];
        float4 r;
        r.x = v.x > kth ? v.x : -10.0f;
        r.y = v.y > kth ? v.y : -10.0f;
        r.z = v.z > kth ? v.z : -10.0f;
        r.w = v.w > kth ? v.w : -10.0f;
        out[i] = r;
    }
}

// ===========================================================================

extern "C" void kernel_launch(void* const* d_in, const int* in_sizes, int n_in,
                              void* d_out, int out_size, void* d_ws, size_t ws_size,
                              hipStream_t stream) {
    (void)n_in; (void)out_size;
    const float* x = (const float*)d_in[0];
    float* out = (float*)d_out;
    const long long n = (long long)in_sizes[0];         // 33,554,432
    const long long n4 = n / 4;
    const long long k0 = (long long)((double)n * 0.9);  // matches Python int(n*0.9)

    float* gelu_out   = out;            // [0, n)
    float* xsaved_out = out + n;        // [n, 2n)
    float* kth_out    = out + 2 * n;    // [2n]

    // ws layout: h12s[4096] | h12b[12288] | h8c[256] | ccnt,below | sel[8] | pad,
    // then cand[cap] uint2.
    const int HDR_U32 = 4096 + 12288 + 256 + 64;
    const size_t hdr_bytes = (size_t)HDR_U32 * sizeof(unsigned);

    if (ws_size >= hdr_bytes + (size_t)32 * 1024 * 1024) {
        unsigned* h12s    = (unsigned*)d_ws;
        unsigned* h12b    = h12s + 4096;
        unsigned* h8c     = h12b + 12288;
        unsigned* ccnt    = h8c + 256;
        unsigned* below_g = ccnt + 1;
        unsigned* sel     = ccnt + 16;
        unsigned cap = (unsigned)((ws_size - hdr_bytes) / sizeof(uint2));
        uint2* cand = (uint2*)((char*)d_ws + hdr_bytes);

        // sample ranks: 524288 float4 * 4 = 2,097,152 values, 90th pct rank
        const long long rank_s = (long long)(2097152.0 * 0.9);

        k_zero<<<(HDR_U32 + THREADS - 1) / THREADS, THREADS, 0, stream>>>((unsigned*)d_ws, HDR_U32);
        k_sample_hist<<<SAMPLE_BLOCKS, THREADS, 0, stream>>>((const float4*)x, h12s, n4);
        k_selectA<<<1, THREADS, 0, stream>>>(h12s, sel, rank_s);
        k_fused_all<<<2048, THREADS, 0, stream>>>((const float4*)x, (float4*)gelu_out,
                                                  (float4*)xsaved_out, sel,
                                                  cand, ccnt, below_g, cap, n4);
        k_cand_hist<<<32, THREADS, 0, stream>>>(cand, ccnt, cap, sel, h12b);
        k_selectB<<<1, THREADS, 0, stream>>>(h12b, below_g, sel, k0);
        k_cand_hist8<<<32, THREADS, 0, stream>>>(cand, ccnt, cap, sel, h8c);
        k_selectC<<<1, THREADS, 0, stream>>>(h8c, sel, kth_out);
        k_finalize<<<512, THREADS, 0, stream>>>(cand, ccnt, cap, xsaved_out, sel);
    } else {
        // Fallback: proven R1 4-pass path (needs only ~34 KB of ws).
        unsigned* h8   = (unsigned*)d_ws;
        unsigned* h12a = h8 + 256;
        unsigned* h12b = h12a + 4096;
        const int FB_U32 = 256 + 4096 + 4096;
        k_zero<<<(FB_U32 + THREADS - 1) / THREADS, THREADS, 0, stream>>>((unsigned*)d_ws, FB_U32);
        const int blocks = 2048;
        k_gelu_hist8<<<blocks, THREADS, 0, stream>>>((const float4*)x, (float4*)gelu_out, h8, n4);
        k_hist12_fb<<<blocks, THREADS, 0, stream>>>((const float4*)x, n4, k0, h8, h12a, h12a, 0);
        k_hist12_fb<<<blocks, THREADS, 0, stream>>>((const float4*)x, n4, k0, h8, h12a, h12b, 1);
        k_xsaved_fb<<<blocks, THREADS, 0, stream>>>((const float4*)x, (float4*)xsaved_out, kth_out,
                                                    h8, h12a, h12b, k0, n4);
    }
}